// Round 1
// baseline (1153.323 us; speedup 1.0000x reference)
//
#include <hip/hip_runtime.h>
#include <hip/hip_bf16.h>

#define Mdim 4096
#define Kdim 4096
#define Ndim 12288

typedef __attribute__((ext_vector_type(8))) short short8;
typedef __attribute__((ext_vector_type(4))) float floatx4;
typedef __attribute__((ext_vector_type(4))) unsigned short ushortx4;

static __device__ __forceinline__ unsigned short f2bf(float x) {
    __hip_bfloat16 h = __float2bfloat16(x);
    return __builtin_bit_cast(unsigned short, h);
}

// 128x128x64 tile, 256 threads (4 waves, 2x2), 16x16x32 bf16 MFMA, 4x4 tiles/wave.
// LDS rows padded to 72 shorts (144 B = 9*16 B): 16B-aligned b128 frag reads,
// worst bank aliasing 2-way (free per m136).
__global__ void __launch_bounds__(256)
w2a16_gemm(const float* __restrict__ X, const int* __restrict__ Q,
           const float* __restrict__ S, const float* __restrict__ Z,
           const float* __restrict__ bias, float* __restrict__ O)
{
    __shared__ unsigned short As[128][72];   // A[m][k] bf16
    __shared__ unsigned short Bs[128][72];   // W^T: Bs[n][k] bf16

    const int t  = threadIdx.x;
    const int n0 = blockIdx.x * 128;
    const int m0 = blockIdx.y * 128;

    const int wave = t >> 6;
    const int lane = t & 63;
    const int wm   = (wave & 1) * 64;
    const int wn   = (wave >> 1) * 64;
    const int lrow = lane & 15;
    const int quad = lane >> 4;

    floatx4 acc[4][4];
    #pragma unroll
    for (int i = 0; i < 4; ++i)
        #pragma unroll
        for (int j = 0; j < 4; ++j)
            acc[i][j] = floatx4{0.f, 0.f, 0.f, 0.f};

    // A staging map: thread -> (row = t>>4 + 16*i, float4 at col (t&15)*4)
    const int a_row0 = t >> 4;
    const int a_c    = (t & 15) * 4;
    // B staging map: thread owns column n = t&127, k-halves by t>>7, 4 k per iter
    const int b_n  = t & 127;
    const int b_k0 = (t >> 7) * 32;

    for (int k0 = 0; k0 < Kdim; k0 += 64) {
        // ---- A: 128x64 fp32 -> bf16 LDS (coalesced float4 loads) ----
        #pragma unroll
        for (int i = 0; i < 8; ++i) {
            const int row = a_row0 + i * 16;
            const floatx4 v = *reinterpret_cast<const floatx4*>(
                &X[(size_t)(m0 + row) * Kdim + k0 + a_c]);
            ushortx4 w;
            w.x = f2bf(v.x); w.y = f2bf(v.y); w.z = f2bf(v.z); w.w = f2bf(v.w);
            *reinterpret_cast<ushortx4*>(&As[row][a_c]) = w;
        }
        // ---- B: 64x128 int32 codes -> dequant -> transpose into Bs[n][k] ----
        const int g = k0 >> 6;                 // GROUP == 64 == BK: one group/tile
        const float s = S[(size_t)g * Ndim + n0 + b_n];
        const float z = Z[(size_t)g * Ndim + n0 + b_n];
        #pragma unroll
        for (int i = 0; i < 8; ++i) {
            const int kk = b_k0 + i * 4;
            const int* qp = &Q[(size_t)(k0 + kk) * Ndim + n0 + b_n];
            ushortx4 w;
            w.x = f2bf(fmaf((float)qp[0],                 s, z));
            w.y = f2bf(fmaf((float)qp[(size_t)Ndim],      s, z));
            w.z = f2bf(fmaf((float)qp[(size_t)2 * Ndim],  s, z));
            w.w = f2bf(fmaf((float)qp[(size_t)3 * Ndim],  s, z));
            *reinterpret_cast<ushortx4*>(&Bs[b_n][kk]) = w;
        }
        __syncthreads();

        // ---- compute: 2 x (8 ds_read_b128 + 16 MFMA) ----
        #pragma unroll
        for (int kk = 0; kk < 64; kk += 32) {
            short8 af[4], bfr[4];
            #pragma unroll
            for (int i = 0; i < 4; ++i)
                af[i] = *reinterpret_cast<const short8*>(
                    &As[wm + i * 16 + lrow][kk + quad * 8]);
            #pragma unroll
            for (int j = 0; j < 4; ++j)
                bfr[j] = *reinterpret_cast<const short8*>(
                    &Bs[wn + j * 16 + lrow][kk + quad * 8]);
            #pragma unroll
            for (int i = 0; i < 4; ++i)
                #pragma unroll
                for (int j = 0; j < 4; ++j)
                    acc[i][j] = __builtin_amdgcn_mfma_f32_16x16x32_bf16(
                        af[i], bfr[j], acc[i][j], 0, 0, 0);
        }
        __syncthreads();
    }

    // ---- epilogue: C/D layout col=lane&15, row=quad*4+reg ----
    #pragma unroll
    for (int j = 0; j < 4; ++j) {
        const int col = n0 + wn + j * 16 + lrow;
        const float bv = bias[col];
        #pragma unroll
        for (int i = 0; i < 4; ++i) {
            const int rbase = m0 + wm + i * 16 + quad * 4;
            #pragma unroll
            for (int r = 0; r < 4; ++r)
                O[(size_t)(rbase + r) * Ndim + col] = acc[i][j][r] + bv;
        }
    }
}

extern "C" void kernel_launch(void* const* d_in, const int* in_sizes, int n_in,
                              void* d_out, int out_size, void* d_ws, size_t ws_size,
                              hipStream_t stream) {
    const float* X  = (const float*)d_in[0];
    const int*   Q  = (const int*)d_in[1];
    const float* S  = (const float*)d_in[2];
    const float* Z  = (const float*)d_in[3];
    const float* Bi = (const float*)d_in[4];
    float* O = (float*)d_out;

    dim3 grid(Ndim / 128, Mdim / 128);   // (96, 32)
    dim3 block(256);
    hipLaunchKernelGGL(w2a16_gemm, grid, block, 0, stream, X, Q, S, Z, Bi, O);
}

// Round 2
// 945.703 us; speedup vs baseline: 1.2195x; 1.2195x over previous
//
#include <hip/hip_runtime.h>
#include <hip/hip_bf16.h>

#define Mdim 4096
#define Kdim 4096
#define Ndim 12288

typedef __attribute__((ext_vector_type(8))) short short8;
typedef __attribute__((ext_vector_type(4))) float floatx4;
typedef __attribute__((ext_vector_type(4))) unsigned short ushortx4;
typedef __attribute__((ext_vector_type(8))) unsigned short ushortx8;

static __device__ __forceinline__ unsigned short f2bf(float x) {
    __hip_bfloat16 h = __float2bfloat16(x);
    return __builtin_bit_cast(unsigned short, h);
}

// async 16B global -> LDS (wave-uniform LDS base + lane*16 semantics)
static __device__ __forceinline__ void gload_lds16(const unsigned short* g, unsigned short* l) {
    __builtin_amdgcn_global_load_lds(
        (const __attribute__((address_space(1))) unsigned int*)g,
        (__attribute__((address_space(3))) unsigned int*)l,
        16, 0, 0);
}

// ---------------- Pre-pass 1: dequant Q[k][n] int32 codes -> Wt[n][k] bf16 ----
// 64x64 tile per block, transpose through LDS.
__global__ void __launch_bounds__(256)
dequant_transpose(const int* __restrict__ Q, const float* __restrict__ S,
                  const float* __restrict__ Z, unsigned short* __restrict__ Wt)
{
    __shared__ unsigned short Ls[64][72];   // [n][k], +8 pad keeps rows 16B-aligned
    const int t  = threadIdx.x;
    const int k0 = blockIdx.x * 64;
    const int n0 = blockIdx.y * 64;
    const int g  = k0 >> 6;                 // GROUP == 64

    const int nc  = (t & 15) * 4;
    const int kr0 = t >> 4;                 // 0..15
    const floatx4 s4 = *reinterpret_cast<const floatx4*>(&S[(size_t)g * Ndim + n0 + nc]);
    const floatx4 z4 = *reinterpret_cast<const floatx4*>(&Z[(size_t)g * Ndim + n0 + nc]);

    #pragma unroll
    for (int i = 0; i < 4; ++i) {
        const int kr = kr0 + i * 16;
        const int4 q = *reinterpret_cast<const int4*>(&Q[(size_t)(k0 + kr) * Ndim + n0 + nc]);
        Ls[nc + 0][kr] = f2bf(fmaf((float)q.x, s4.x, z4.x));
        Ls[nc + 1][kr] = f2bf(fmaf((float)q.y, s4.y, z4.y));
        Ls[nc + 2][kr] = f2bf(fmaf((float)q.z, s4.z, z4.z));
        Ls[nc + 3][kr] = f2bf(fmaf((float)q.w, s4.w, z4.w));
    }
    __syncthreads();

    const int n  = t >> 2;                  // 0..63
    const int kc = (t & 3) * 16;            // 0,16,32,48
    const ushortx8 a = *reinterpret_cast<const ushortx8*>(&Ls[n][kc]);
    const ushortx8 b = *reinterpret_cast<const ushortx8*>(&Ls[n][kc + 8]);
    unsigned short* dst = &Wt[(size_t)(n0 + n) * Kdim + k0 + kc];
    *reinterpret_cast<ushortx8*>(dst)     = a;
    *reinterpret_cast<ushortx8*>(dst + 8) = b;
}

// ---------------- Pre-pass 2: X fp32 -> bf16 (same [M][K] layout) -------------
__global__ void __launch_bounds__(256)
xconv(const float* __restrict__ X, unsigned short* __restrict__ Xw)
{
    const size_t i = ((size_t)blockIdx.x * 256 + threadIdx.x) * 8;
    const floatx4 a = *reinterpret_cast<const floatx4*>(&X[i]);
    const floatx4 b = *reinterpret_cast<const floatx4*>(&X[i + 4]);
    ushortx8 w;
    w[0] = f2bf(a.x); w[1] = f2bf(a.y); w[2] = f2bf(a.z); w[3] = f2bf(a.w);
    w[4] = f2bf(b.x); w[5] = f2bf(b.y); w[6] = f2bf(b.z); w[7] = f2bf(b.w);
    *reinterpret_cast<ushortx8*>(&Xw[i]) = w;
}

// ---------------- Main GEMM: m97 structure, all-bf16, global_load_lds ---------
// 128x128x64 tile, 256 threads (2x2 waves), 4x4 of 16x16x32 MFMA per wave.
// LDS unpadded [row][64] (required by global_load_lds lane ordering).
__global__ void __launch_bounds__(256)
gemm_bf16(const unsigned short* __restrict__ A, const unsigned short* __restrict__ B,
          const float* __restrict__ bias, float* __restrict__ O)
{
    __shared__ unsigned short As[128 * 64];
    __shared__ unsigned short Bs[128 * 64];

    // supergroup swizzle: 8 m-blocks share each B panel among concurrent blocks
    const int nblk = Ndim / 128;            // 96
    const int gsz  = 8 * nblk;
    const int grp  = blockIdx.x / gsz;
    const int r    = blockIdx.x % gsz;
    const int m0   = (grp * 8 + (r & 7)) * 128;
    const int n0   = (r >> 3) * 128;

    const int t    = threadIdx.x;
    const int wave = t >> 6;
    const int lane = t & 63;
    const int wm   = (wave & 1) * 64;
    const int wn   = (wave >> 1) * 64;
    const int lrow = lane & 15;
    const int quad = lane >> 4;

    // staging: wave stages rows [wave*32, wave*32+32), 8 rows per call
    const int srow = lane >> 3;             // 0..7
    const int scol = (lane & 7) * 8;        // shorts (16 B)
    const unsigned short* Ag = &A[(size_t)(m0 + wave * 32 + srow) * Kdim + scol];
    const unsigned short* Bg = &B[(size_t)(n0 + wave * 32 + srow) * Kdim + scol];
    unsigned short* AsB = &As[(wave * 32) * 64];
    unsigned short* BsB = &Bs[(wave * 32) * 64];

    floatx4 acc[4][4];
    #pragma unroll
    for (int i = 0; i < 4; ++i)
        #pragma unroll
        for (int j = 0; j < 4; ++j)
            acc[i][j] = floatx4{0.f, 0.f, 0.f, 0.f};

    for (int k0 = 0; k0 < Kdim; k0 += 64) {
        #pragma unroll
        for (int it = 0; it < 4; ++it) {
            gload_lds16(Ag + (size_t)(it * 8) * Kdim + k0, AsB + it * 8 * 64);
            gload_lds16(Bg + (size_t)(it * 8) * Kdim + k0, BsB + it * 8 * 64);
        }
        __syncthreads();

        #pragma unroll
        for (int kk = 0; kk < 64; kk += 32) {
            short8 af[4], bfr[4];
            #pragma unroll
            for (int i = 0; i < 4; ++i)
                af[i] = *reinterpret_cast<const short8*>(
                    &As[(wm + i * 16 + lrow) * 64 + kk + quad * 8]);
            #pragma unroll
            for (int j = 0; j < 4; ++j)
                bfr[j] = *reinterpret_cast<const short8*>(
                    &Bs[(wn + j * 16 + lrow) * 64 + kk + quad * 8]);
            #pragma unroll
            for (int i = 0; i < 4; ++i)
                #pragma unroll
                for (int j = 0; j < 4; ++j)
                    acc[i][j] = __builtin_amdgcn_mfma_f32_16x16x32_bf16(
                        af[i], bfr[j], acc[i][j], 0, 0, 0);
        }
        __syncthreads();
    }

    #pragma unroll
    for (int j = 0; j < 4; ++j) {
        const int col = n0 + wn + j * 16 + lrow;
        const float bv = bias[col];
        #pragma unroll
        for (int i = 0; i < 4; ++i) {
            const int rbase = m0 + wm + i * 16 + quad * 4;
            #pragma unroll
            for (int rr = 0; rr < 4; ++rr)
                O[(size_t)(rbase + rr) * Ndim + col] = acc[i][j][rr] + bv;
        }
    }
}

// ---------------- Fallback (round-1 fused kernel) if ws too small -------------
__global__ void __launch_bounds__(256)
w2a16_gemm_fb(const float* __restrict__ X, const int* __restrict__ Q,
              const float* __restrict__ S, const float* __restrict__ Z,
              const float* __restrict__ bias, float* __restrict__ O)
{
    __shared__ unsigned short As[128][72];
    __shared__ unsigned short Bs[128][72];
    const int t  = threadIdx.x;
    const int n0 = blockIdx.x * 128;
    const int m0 = blockIdx.y * 128;
    const int wave = t >> 6, lane = t & 63;
    const int wm = (wave & 1) * 64, wn = (wave >> 1) * 64;
    const int lrow = lane & 15, quad = lane >> 4;
    floatx4 acc[4][4];
    #pragma unroll
    for (int i = 0; i < 4; ++i)
        #pragma unroll
        for (int j = 0; j < 4; ++j) acc[i][j] = floatx4{0.f, 0.f, 0.f, 0.f};
    const int a_row0 = t >> 4, a_c = (t & 15) * 4;
    const int b_n = t & 127, b_k0 = (t >> 7) * 32;
    for (int k0 = 0; k0 < Kdim; k0 += 64) {
        #pragma unroll
        for (int i = 0; i < 8; ++i) {
            const int row = a_row0 + i * 16;
            const floatx4 v = *reinterpret_cast<const floatx4*>(
                &X[(size_t)(m0 + row) * Kdim + k0 + a_c]);
            ushortx4 w;
            w.x = f2bf(v.x); w.y = f2bf(v.y); w.z = f2bf(v.z); w.w = f2bf(v.w);
            *reinterpret_cast<ushortx4*>(&As[row][a_c]) = w;
        }
        const int g = k0 >> 6;
        const float s = S[(size_t)g * Ndim + n0 + b_n];
        const float z = Z[(size_t)g * Ndim + n0 + b_n];
        #pragma unroll
        for (int i = 0; i < 8; ++i) {
            const int kk = b_k0 + i * 4;
            const int* qp = &Q[(size_t)(k0 + kk) * Ndim + n0 + b_n];
            ushortx4 w;
            w.x = f2bf(fmaf((float)qp[0],                s, z));
            w.y = f2bf(fmaf((float)qp[(size_t)Ndim],     s, z));
            w.z = f2bf(fmaf((float)qp[(size_t)2 * Ndim], s, z));
            w.w = f2bf(fmaf((float)qp[(size_t)3 * Ndim], s, z));
            *reinterpret_cast<ushortx4*>(&Bs[b_n][kk]) = w;
        }
        __syncthreads();
        #pragma unroll
        for (int kk = 0; kk < 64; kk += 32) {
            short8 af[4], bfr[4];
            #pragma unroll
            for (int i = 0; i < 4; ++i)
                af[i] = *reinterpret_cast<const short8*>(&As[wm + i * 16 + lrow][kk + quad * 8]);
            #pragma unroll
            for (int j = 0; j < 4; ++j)
                bfr[j] = *reinterpret_cast<const short8*>(&Bs[wn + j * 16 + lrow][kk + quad * 8]);
            #pragma unroll
            for (int i = 0; i < 4; ++i)
                #pragma unroll
                for (int j = 0; j < 4; ++j)
                    acc[i][j] = __builtin_amdgcn_mfma_f32_16x16x32_bf16(af[i], bfr[j], acc[i][j], 0, 0, 0);
        }
        __syncthreads();
    }
    #pragma unroll
    for (int j = 0; j < 4; ++j) {
        const int col = n0 + wn + j * 16 + lrow;
        const float bv = bias[col];
        #pragma unroll
        for (int i = 0; i < 4; ++i) {
            const int rbase = m0 + wm + i * 16 + quad * 4;
            #pragma unroll
            for (int rr = 0; rr < 4; ++rr)
                O[(size_t)(rbase + rr) * Ndim + col] = acc[i][j][rr] + bv;
        }
    }
}

extern "C" void kernel_launch(void* const* d_in, const int* in_sizes, int n_in,
                              void* d_out, int out_size, void* d_ws, size_t ws_size,
                              hipStream_t stream) {
    const float* X  = (const float*)d_in[0];
    const int*   Q  = (const int*)d_in[1];
    const float* S  = (const float*)d_in[2];
    const float* Z  = (const float*)d_in[3];
    const float* Bi = (const float*)d_in[4];
    float* O = (float*)d_out;

    const size_t wt_bytes = (size_t)Kdim * Ndim * 2;      // 100,663,296
    const size_t xw_bytes = (size_t)Mdim * Kdim * 2;      //  33,554,432

    if (ws_size >= wt_bytes + xw_bytes) {
        unsigned short* Wt = (unsigned short*)d_ws;
        unsigned short* Xw = (unsigned short*)((char*)d_ws + wt_bytes);

        dim3 g1(Kdim / 64, Ndim / 64);                    // (64, 192)
        hipLaunchKernelGGL(dequant_transpose, g1, dim3(256), 0, stream, Q, S, Z, Wt);

        const int xblocks = (Mdim * Kdim) / (256 * 8);    // 8192
        hipLaunchKernelGGL(xconv, dim3(xblocks), dim3(256), 0, stream, X, Xw);

        const int nblocks = (Mdim / 128) * (Ndim / 128);  // 3072
        hipLaunchKernelGGL(gemm_bf16, dim3(nblocks), dim3(256), 0, stream, Xw, Wt, Bi, O);
    } else {
        dim3 grid(Ndim / 128, Mdim / 128);
        hipLaunchKernelGGL(w2a16_gemm_fb, grid, dim3(256), 0, stream, X, Q, S, Z, Bi, O);
    }
}

// Round 3
// 853.805 us; speedup vs baseline: 1.3508x; 1.1076x over previous
//
#include <hip/hip_runtime.h>
#include <hip/hip_bf16.h>

#define Mdim 4096
#define Kdim 4096
#define Ndim 12288

typedef __attribute__((ext_vector_type(8))) short short8;
typedef __attribute__((ext_vector_type(4))) float floatx4;
typedef __attribute__((ext_vector_type(4))) int intx4;
typedef __attribute__((ext_vector_type(4))) unsigned short ushortx4;
typedef __attribute__((ext_vector_type(8))) unsigned short ushortx8;

static __device__ __forceinline__ unsigned short f2bf(float x) {
    __hip_bfloat16 h = __float2bfloat16(x);
    return __builtin_bit_cast(unsigned short, h);
}

// async 16B global -> LDS (LDS dst = wave-uniform base + lane*16)
static __device__ __forceinline__ void gload_lds16(const unsigned short* g, unsigned short* l) {
    __builtin_amdgcn_global_load_lds(
        (const __attribute__((address_space(1))) unsigned int*)g,
        (__attribute__((address_space(3))) unsigned int*)l,
        16, 0, 0);
}

// ---------------- Pre-pass 1: Q[k][n] int32 codes -> Wt[n][k] bf16 -----------
// 256k x 64n per block; in-register 4x4 transpose; vector LDS ops.
__global__ void __launch_bounds__(256)
dequant_transpose(const int* __restrict__ Q, const float* __restrict__ S,
                  const float* __restrict__ Z, unsigned short* __restrict__ Wt)
{
    __shared__ unsigned short Ls[64][72];    // [n][k], 144 B rows (16B-aligned)
    const int t     = threadIdx.x;
    const int kbase = blockIdx.x * 256;
    const int n0    = blockIdx.y * 64;
    const int tn = t & 15, tk = t >> 4;      // tn: n-group of 4, tk: k-group of 4
    const int nc = tn * 4;
    const int n_out  = t >> 2;               // 0..63
    const int kc_out = (t & 3) * 16;         // 0,16,32,48

    #pragma unroll
    for (int s = 0; s < 4; ++s) {
        const int k0 = kbase + s * 64;
        const int g  = k0 >> 6;              // GROUP == 64
        const floatx4 s4 = *reinterpret_cast<const floatx4*>(&S[(size_t)g * Ndim + n0 + nc]);
        const floatx4 z4 = *reinterpret_cast<const floatx4*>(&Z[(size_t)g * Ndim + n0 + nc]);
        intx4 q[4];
        #pragma unroll
        for (int r = 0; r < 4; ++r)
            q[r] = *reinterpret_cast<const intx4*>(&Q[(size_t)(k0 + tk * 4 + r) * Ndim + n0 + nc]);
        if (s) __syncthreads();              // Ls reuse hazard
        #pragma unroll
        for (int j = 0; j < 4; ++j) {
            const float sv = s4[j], zv = z4[j];
            ushortx4 w;
            w.x = f2bf(fmaf((float)q[0][j], sv, zv));
            w.y = f2bf(fmaf((float)q[1][j], sv, zv));
            w.z = f2bf(fmaf((float)q[2][j], sv, zv));
            w.w = f2bf(fmaf((float)q[3][j], sv, zv));
            *reinterpret_cast<ushortx4*>(&Ls[nc + j][tk * 4]) = w;
        }
        __syncthreads();
        const ushortx8 a = *reinterpret_cast<const ushortx8*>(&Ls[n_out][kc_out]);
        const ushortx8 b = *reinterpret_cast<const ushortx8*>(&Ls[n_out][kc_out + 8]);
        unsigned short* dst = &Wt[(size_t)(n0 + n_out) * Kdim + k0 + kc_out];
        *reinterpret_cast<ushortx8*>(dst)     = a;
        *reinterpret_cast<ushortx8*>(dst + 8) = b;
    }
}

// ---------------- Pre-pass 2: X fp32 -> bf16 ---------------------------------
__global__ void __launch_bounds__(256)
xconv(const float* __restrict__ X, unsigned short* __restrict__ Xw)
{
    const size_t i = ((size_t)blockIdx.x * 256 + threadIdx.x) * 8;
    const floatx4 a = *reinterpret_cast<const floatx4*>(&X[i]);
    const floatx4 b = *reinterpret_cast<const floatx4*>(&X[i + 4]);
    ushortx8 w;
    w[0] = f2bf(a.x); w[1] = f2bf(a.y); w[2] = f2bf(a.z); w[3] = f2bf(a.w);
    w[4] = f2bf(b.x); w[5] = f2bf(b.y); w[6] = f2bf(b.z); w[7] = f2bf(b.w);
    *reinterpret_cast<ushortx8*>(&Xw[i]) = w;
}

// ---------------- Main GEMM: XOR-swizzled LDS, global_load_lds ---------------
// 128x128x64 tile, 256 threads (2x2 waves), 4x4 of 16x16x32 bf16 MFMA.
// LDS rows = 64 shorts; 16B chunk c stored at physical chunk c ^ (row&7).
__global__ void __launch_bounds__(256)
gemm_bf16(const unsigned short* __restrict__ A, const unsigned short* __restrict__ B,
          const float* __restrict__ bias, float* __restrict__ O)
{
    __shared__ unsigned short As[128 * 64];
    __shared__ unsigned short Bs[128 * 64];

    const int nblk = Ndim / 128;            // 96
    const int gsz  = 8 * nblk;
    const int grp  = blockIdx.x / gsz;
    const int r    = blockIdx.x % gsz;
    const int m0   = (grp * 8 + (r & 7)) * 128;
    const int n0   = (r >> 3) * 128;

    const int t    = threadIdx.x;
    const int wave = t >> 6;
    const int lane = t & 63;
    const int wm   = (wave & 1) * 64;
    const int wn   = (wave >> 1) * 64;
    const int lrow = lane & 15;
    const int quad = lane >> 4;
    const int lsw  = lrow & 7;              // row&7 for this lane's fragment rows

    // staging: lane ℓ fills physical chunk ℓ&7 of row ℓ>>3 within an 8-row slab;
    // that chunk must hold logical k-chunk (ℓ&7)^(ℓ>>3)  (row&7 == ℓ>>3)
    const int srow = lane >> 3;
    const int scol = ((lane & 7) ^ srow) * 8;
    const unsigned short* Ag = &A[(size_t)(m0 + wave * 32 + srow) * Kdim + scol];
    const unsigned short* Bg = &B[(size_t)(n0 + wave * 32 + srow) * Kdim + scol];
    unsigned short* AsB = &As[(wave * 32) * 64];
    unsigned short* BsB = &Bs[(wave * 32) * 64];

    floatx4 acc[4][4];
    #pragma unroll
    for (int i = 0; i < 4; ++i)
        #pragma unroll
        for (int j = 0; j < 4; ++j)
            acc[i][j] = floatx4{0.f, 0.f, 0.f, 0.f};

    for (int k0 = 0; k0 < Kdim; k0 += 64) {
        #pragma unroll
        for (int it = 0; it < 4; ++it) {
            gload_lds16(Ag + (size_t)(it * 8) * Kdim + k0, AsB + it * 8 * 64);
            gload_lds16(Bg + (size_t)(it * 8) * Kdim + k0, BsB + it * 8 * 64);
        }
        __syncthreads();

        #pragma unroll
        for (int kk = 0; kk < 64; kk += 32) {
            const int cphys = (((kk >> 3) + quad) ^ lsw) * 8;   // swizzled chunk
            short8 af[4], bfr[4];
            #pragma unroll
            for (int i = 0; i < 4; ++i)
                af[i] = *reinterpret_cast<const short8*>(
                    &As[(wm + i * 16 + lrow) * 64 + cphys]);
            #pragma unroll
            for (int j = 0; j < 4; ++j)
                bfr[j] = *reinterpret_cast<const short8*>(
                    &Bs[(wn + j * 16 + lrow) * 64 + cphys]);
            #pragma unroll
            for (int i = 0; i < 4; ++i)
                #pragma unroll
                for (int j = 0; j < 4; ++j)
                    acc[i][j] = __builtin_amdgcn_mfma_f32_16x16x32_bf16(
                        af[i], bfr[j], acc[i][j], 0, 0, 0);
        }
        __syncthreads();
    }

    #pragma unroll
    for (int j = 0; j < 4; ++j) {
        const int col = n0 + wn + j * 16 + lrow;
        const float bv = bias[col];
        #pragma unroll
        for (int i = 0; i < 4; ++i) {
            const int rbase = m0 + wm + i * 16 + quad * 4;
            #pragma unroll
            for (int rr = 0; rr < 4; ++rr)
                O[(size_t)(rbase + rr) * Ndim + col] = acc[i][j][rr] + bv;
        }
    }
}

// ---------------- Fallback (fused, ws-independent) ---------------------------
__global__ void __launch_bounds__(256)
w2a16_gemm_fb(const float* __restrict__ X, const int* __restrict__ Q,
              const float* __restrict__ S, const float* __restrict__ Z,
              const float* __restrict__ bias, float* __restrict__ O)
{
    __shared__ unsigned short As[128][72];
    __shared__ unsigned short Bs[128][72];
    const int t  = threadIdx.x;
    const int n0 = blockIdx.x * 128;
    const int m0 = blockIdx.y * 128;
    const int wave = t >> 6, lane = t & 63;
    const int wm = (wave & 1) * 64, wn = (wave >> 1) * 64;
    const int lrow = lane & 15, quad = lane >> 4;
    floatx4 acc[4][4];
    #pragma unroll
    for (int i = 0; i < 4; ++i)
        #pragma unroll
        for (int j = 0; j < 4; ++j) acc[i][j] = floatx4{0.f, 0.f, 0.f, 0.f};
    const int a_row0 = t >> 4, a_c = (t & 15) * 4;
    const int b_n = t & 127, b_k0 = (t >> 7) * 32;
    for (int k0 = 0; k0 < Kdim; k0 += 64) {
        #pragma unroll
        for (int i = 0; i < 8; ++i) {
            const int row = a_row0 + i * 16;
            const floatx4 v = *reinterpret_cast<const floatx4*>(
                &X[(size_t)(m0 + row) * Kdim + k0 + a_c]);
            ushortx4 w;
            w.x = f2bf(v.x); w.y = f2bf(v.y); w.z = f2bf(v.z); w.w = f2bf(v.w);
            *reinterpret_cast<ushortx4*>(&As[row][a_c]) = w;
        }
        const int g = k0 >> 6;
        const float s = S[(size_t)g * Ndim + n0 + b_n];
        const float z = Z[(size_t)g * Ndim + n0 + b_n];
        #pragma unroll
        for (int i = 0; i < 8; ++i) {
            const int kk = b_k0 + i * 4;
            const int* qp = &Q[(size_t)(k0 + kk) * Ndim + n0 + b_n];
            ushortx4 w;
            w.x = f2bf(fmaf((float)qp[0],                s, z));
            w.y = f2bf(fmaf((float)qp[(size_t)Ndim],     s, z));
            w.z = f2bf(fmaf((float)qp[(size_t)2 * Ndim], s, z));
            w.w = f2bf(fmaf((float)qp[(size_t)3 * Ndim], s, z));
            *reinterpret_cast<ushortx4*>(&Bs[b_n][kk]) = w;
        }
        __syncthreads();
        #pragma unroll
        for (int kk = 0; kk < 64; kk += 32) {
            short8 af[4], bfr[4];
            #pragma unroll
            for (int i = 0; i < 4; ++i)
                af[i] = *reinterpret_cast<const short8*>(&As[wm + i * 16 + lrow][kk + quad * 8]);
            #pragma unroll
            for (int j = 0; j < 4; ++j)
                bfr[j] = *reinterpret_cast<const short8*>(&Bs[wn + j * 16 + lrow][kk + quad * 8]);
            #pragma unroll
            for (int i = 0; i < 4; ++i)
                #pragma unroll
                for (int j = 0; j < 4; ++j)
                    acc[i][j] = __builtin_amdgcn_mfma_f32_16x16x32_bf16(af[i], bfr[j], acc[i][j], 0, 0, 0);
        }
        __syncthreads();
    }
    #pragma unroll
    for (int j = 0; j < 4; ++j) {
        const int col = n0 + wn + j * 16 + lrow;
        const float bv = bias[col];
        #pragma unroll
        for (int i = 0; i < 4; ++i) {
            const int rbase = m0 + wm + i * 16 + quad * 4;
            #pragma unroll
            for (int rr = 0; rr < 4; ++rr)
                O[(size_t)(rbase + rr) * Ndim + col] = acc[i][j][rr] + bv;
        }
    }
}

extern "C" void kernel_launch(void* const* d_in, const int* in_sizes, int n_in,
                              void* d_out, int out_size, void* d_ws, size_t ws_size,
                              hipStream_t stream) {
    const float* X  = (const float*)d_in[0];
    const int*   Q  = (const int*)d_in[1];
    const float* S  = (const float*)d_in[2];
    const float* Z  = (const float*)d_in[3];
    const float* Bi = (const float*)d_in[4];
    float* O = (float*)d_out;

    const size_t wt_bytes = (size_t)Kdim * Ndim * 2;
    const size_t xw_bytes = (size_t)Mdim * Kdim * 2;

    if (ws_size >= wt_bytes + xw_bytes) {
        unsigned short* Wt = (unsigned short*)d_ws;
        unsigned short* Xw = (unsigned short*)((char*)d_ws + wt_bytes);

        dim3 g1(Kdim / 256, Ndim / 64);                   // (16, 192)
        hipLaunchKernelGGL(dequant_transpose, g1, dim3(256), 0, stream, Q, S, Z, Wt);

        const int xblocks = (Mdim * Kdim) / (256 * 8);    // 8192
        hipLaunchKernelGGL(xconv, dim3(xblocks), dim3(256), 0, stream, X, Xw);

        const int nblocks = (Mdim / 128) * (Ndim / 128);  // 3072
        hipLaunchKernelGGL(gemm_bf16, dim3(nblocks), dim3(256), 0, stream, Xw, Wt, Bi, O);
    } else {
        dim3 grid(Ndim / 128, Mdim / 128);
        hipLaunchKernelGGL(w2a16_gemm_fb, grid, dim3(256), 0, stream, X, Q, S, Z, Bi, O);
    }
}